// Round 1
// 217.408 us; speedup vs baseline: 1.1241x; 1.1241x over previous
//
#include <hip/hip_runtime.h>
#include <stdint.h>

// ---- Problem constants ----
#define NDRUGS 10000
#define NTAILS 20000
#define NE     1000000
#define SSIZE  16
#define NPART  192          // partial-histogram blocks (u16 partials, 3.84 MB)
#define CSLOT  96           // candidate slots per drug

typedef unsigned int  u32;
typedef unsigned short u16;
typedef unsigned long long u64;
typedef __attribute__((ext_vector_type(8))) short bf16x8;
typedef __attribute__((ext_vector_type(4))) float f32x4;
#define U64MAX 0xffffffffffffffffULL

// ---- Threefry-2x32-20 (exact JAX semantics) ----
__host__ __device__ __forceinline__ void tf2x32(u32 k0, u32 k1, u32 x0, u32 x1,
                                                u32& o0, u32& o1) {
  u32 ks2 = k0 ^ k1 ^ 0x1BD11BDAu;
  x0 += k0; x1 += k1;
#define TFR(r) { x0 += x1; x1 = (x1 << r) | (x1 >> (32 - r)); x1 ^= x0; }
  TFR(13) TFR(15) TFR(26) TFR(6)
  x0 += k1; x1 += ks2 + 1u;
  TFR(17) TFR(29) TFR(16) TFR(24)
  x0 += ks2; x1 += k0 + 2u;
  TFR(13) TFR(15) TFR(26) TFR(6)
  x0 += k0; x1 += k1 + 3u;
  TFR(17) TFR(29) TFR(16) TFR(24)
  x0 += k1; x1 += ks2 + 4u;
  TFR(13) TFR(15) TFR(26) TFR(6)
  x0 += ks2; x1 += k0 + 5u;
#undef TFR
  o0 = x0; o1 = x1;
}

__device__ __forceinline__ u32 rbits32(u32 kx, u32 ky, u32 i) {
  u32 o0, o1;
  tf2x32(kx, ky, 0u, i, o0, o1);
  return o0 ^ o1;   // partitionable fold
}
// Stable-lexsort-equivalent composite key
#define SELKEY(e) ((((u64)(rbits32(k1x, k1y, (u32)(e)) >> 9)) << 32) | (u32)(e))
#define CSWAP(x, y) { u64 lo_ = x < y ? x : y; u64 hi_ = x < y ? y : x; x = lo_; y = hi_; }

// ---- bf16 helpers (RNE, matches np/jax bf16 cast) ----
__device__ __forceinline__ float q16(float f) {
  u32 x = __builtin_bit_cast(u32, f);
  u32 lsb = (x >> 16) & 1u;
  x = (x + 0x7fffu + lsb) & 0xffff0000u;
  return __builtin_bit_cast(float, x);
}
__device__ __forceinline__ u16 rne16(float f) {
  u32 x = __builtin_bit_cast(u32, f);
  u32 lsb = (x >> 16) & 1u;
  return (u16)((x + 0x7fffu + lsb) >> 16);
}
__device__ __forceinline__ float bfbits2f(u16 b) {
  u32 x = ((u32)b) << 16;
  return __builtin_bit_cast(float, x);
}

// ---- Phase 1: degree histogram via per-block LDS hist + u16 partials ----
// Replaces 1M scattered L2 atomics (42 us, line-serialized) with LDS atomics
// + coalesced partial stores. Per-block edge count <= ~5.2K so u16 is safe.
__global__ __launch_bounds__(256) void k_hist(const int4* __restrict__ dkg4,
                                              u32* __restrict__ part32) {
  __shared__ int hist[NDRUGS];                 // 40 KB
  for (int j = threadIdx.x; j < NDRUGS; j += 256) hist[j] = 0;
  __syncthreads();
  for (int i = blockIdx.x * 256 + threadIdx.x; i < NE / 4; i += NPART * 256) {
    int4 A = dkg4[3 * i], B = dkg4[3 * i + 1], C = dkg4[3 * i + 2];
    atomicAdd(&hist[A.x], 1);
    atomicAdd(&hist[A.w], 1);
    atomicAdd(&hist[B.z], 1);
    atomicAdd(&hist[C.y], 1);
  }
  __syncthreads();
  u32* p = part32 + blockIdx.x * (NDRUGS / 2);
  for (int j = threadIdx.x; j < NDRUGS / 2; j += 256)
    p[j] = (u32)hist[2 * j] | ((u32)hist[2 * j + 1] << 16);
}

// ---- Phase 2: reduce partials; per-drug candidate threshold; init cnt/nflag.
// thr guarantees: deg<=40 -> pass-all (exact, covers deg<16 extras);
// else mean ~48 candidates. cnt>=16 => candidates contain the exact top-16.
__global__ __launch_bounds__(256) void k_thr(const u32* __restrict__ part32,
                                             int* __restrict__ deg,
                                             u32* __restrict__ thr,
                                             int* __restrict__ cnt,
                                             int* __restrict__ nflag) {
  int t = blockIdx.x * 256 + threadIdx.x;      // one thread = 2 drugs
  if (t == 0) *nflag = 0;
  if (t >= NDRUGS / 2) return;
  int d0 = 0, d1 = 0;
  for (int b = 0; b < NPART; b++) {
    u32 v = part32[b * (NDRUGS / 2) + t];
    d0 += (int)(v & 0xffffu);
    d1 += (int)(v >> 16);
  }
  int d = 2 * t;
  deg[d] = d0;  deg[d + 1] = d1;
  cnt[d] = 0;   cnt[d + 1] = 0;
  thr[d]     = (d0 <= 40) ? 0x800000u
                          : (402653184u + (u32)d0 - 1u) / (u32)d0;  // ceil(48*2^23/dg)
  thr[d + 1] = (d1 <= 40) ? 0x800000u
                          : (402653184u + (u32)d1 - 1u) / (u32)d1;
}

// ---- Phase 3: candidate emission, SINGLE PASS (thr staged in 40 KB LDS) ----
__global__ __launch_bounds__(256) void k_cand(const int4* __restrict__ dkg4,
                                              const u32* __restrict__ thr,
                                              int* __restrict__ cnt,
                                              int* __restrict__ cand,
                                              int* __restrict__ nflag,
                                              int* __restrict__ flaglist,
                                              u32 k1x, u32 k1y) {
  __shared__ u32 thr_l[NDRUGS];               // 40 KB -> 4 blocks/CU
  for (int j = threadIdx.x; j < NDRUGS; j += 256) thr_l[j] = thr[j];
  __syncthreads();
  int i = blockIdx.x * 256 + threadIdx.x;
  if (i >= NE / 4) return;
  int4 A = dkg4[3 * i], B = dkg4[3 * i + 1], C = dkg4[3 * i + 2];
  int h[4] = {A.x, A.w, B.z, C.y};
  int e0 = 4 * i;
#pragma unroll
  for (int k = 0; k < 4; k++) {
    u32 rb = rbits32(k1x, k1y, (u32)(e0 + k));
    if ((rb >> 9) < thr_l[h[k]]) {
      int pos = atomicAdd(&cnt[h[k]], 1);
      if (pos < CSLOT) cand[h[k] * CSLOT + pos] = e0 + k;
      else if (pos == CSLOT) {
        int ix = atomicAdd(nflag, 1);
        if (ix < 256) flaglist[ix] = h[k];
      }
    }
  }
}

// ---- Phase 4: wave-per-drug top-16 from candidates ----
__global__ __launch_bounds__(256) void k_select(const int* __restrict__ cand,
                                                const int* __restrict__ cnt,
                                                const int* __restrict__ deg,
                                                int* __restrict__ sel,
                                                int* __restrict__ nflag,
                                                int* __restrict__ flaglist,
                                                u32 k1x, u32 k1y,
                                                u32 khx, u32 khy,
                                                u32 klx, u32 kly) {
  __shared__ int asel[4][16];
  int tid = threadIdx.x, lane = tid & 63, wv = tid >> 6;
  int d = blockIdx.x * 4 + wv;
  if (d >= NDRUGS) return;
  int dg = deg[d], n = cnt[d], off = d * CSLOT;
  if (dg <= 0) {
    if (lane < 16) sel[d * SSIZE + lane] = -1;
    return;
  }
  if (dg >= SSIZE) {
    if (n < SSIZE || n > CSLOT) {          // filter failed -> exact fallback
      if (lane == 0) {
        int ix = atomicAdd(nflag, 1);
        if (ix < 256) flaglist[ix] = d;
      }
      return;
    }
    u64 a0 = U64MAX, a1 = U64MAX;
    if (lane < n)      a0 = SELKEY(cand[off + lane]);
    if (lane + 64 < n) a1 = SELKEY(cand[off + lane + 64]);
    CSWAP(a0, a1)
    int h = 0; u32 my = 0;
#pragma unroll
    for (int r = 0; r < SSIZE; r++) {
      u64 ex = (h == 0) ? a0 : (h == 1) ? a1 : U64MAX;
      u64 g = ex;
#pragma unroll
      for (int m = 1; m < 64; m <<= 1) {
        u64 o = __shfl_xor(g, m, 64);
        g = o < g ? o : g;
      }
      if (lane == r) my = (u32)g;
      if (ex == g) h++;
    }
    if (lane < 16) sel[d * SSIZE + lane] = (int)my;
  } else {
    // deg<16: thr passed all -> n == dg; ascending extraction + extras
    u64 a0 = (lane < n) ? SELKEY(cand[off + lane]) : U64MAX;
    int h = 0;
    for (int r = 0; r < n; r++) {
      u64 ex = (h == 0) ? a0 : U64MAX;
      u64 g = ex;
#pragma unroll
      for (int m = 1; m < 64; m <<= 1) {
        u64 o = __shfl_xor(g, m, 64);
        g = o < g ? o : g;
      }
      if (lane == 0) asel[wv][r] = (int)(u32)g;
      if (ex == g) h++;
    }
    if (lane < n) sel[d * SSIZE + lane] = asel[wv][lane];
    int need = SSIZE - n;
    const u32 span = 0x7fffffffu;           // 2^31-1; 2^32 % span = 2
    if (lane < need) {
      u32 j = (u32)(d * SSIZE + lane);
      u32 hi = rbits32(khx, khy, j) % span;
      u32 lo = rbits32(klx, kly, j) % span;
      u32 u = (hi * 2u + lo) % span;        // uint32 wraparound: JAX-exact
      int idx = (int)(u % (u32)n);
      sel[d * SSIZE + n + lane] = asel[wv][idx];
    }
  }
}

// ---- Phase 4b: exact fallback for flagged drugs (normally: load, exit) ----
__global__ __launch_bounds__(256) void k_fix(const int* __restrict__ dkg,
                                             const int* __restrict__ nflag,
                                             const int* __restrict__ flaglist,
                                             int* __restrict__ sel,
                                             u32 k1x, u32 k1y) {
  int nf = *nflag;
  if (nf <= 0) return;
  if (nf > 256) nf = 256;
  __shared__ u64 pool[256 * 16];
  int tid = threadIdx.x;
  for (int f = 0; f < nf; f++) {
    int d = flaglist[f];
    u64 loc[16];
#pragma unroll
    for (int i = 0; i < 16; i++) loc[i] = U64MAX;
    u64 mx = U64MAX; int mi = 0;
    for (int e = tid; e < NE; e += 256) {
      if (dkg[3 * e] == d) {
        u64 k = SELKEY(e);
        if (k < mx) {
          loc[mi] = k; mx = 0;
          for (int i = 0; i < 16; i++)
            if (loc[i] > mx) { mx = loc[i]; mi = i; }
        }
      }
    }
#pragma unroll
    for (int i = 0; i < 16; i++) pool[tid * 16 + i] = loc[i];
    __syncthreads();
    if (tid == 0) {
      u64 best[16];
#pragma unroll
      for (int i = 0; i < 16; i++) best[i] = U64MAX;
      u64 bm = U64MAX; int bi = 0;
      for (int i = 0; i < 256 * 16; i++) {
        u64 k = pool[i];
        if (k < bm) {
          best[bi] = k; bm = 0;
          for (int j = 0; j < 16; j++)
            if (best[j] > bm) { bm = best[j]; bi = j; }
        }
      }
      for (int s = 0; s < 16; s++) sel[d * SSIZE + s] = (int)(u32)best[s];
    }
    __syncthreads();
  }
}

// ---- Phase 5: edge-MLP + neighbor gather via MFMA (4 drugs/wave) ----
__global__ __launch_bounds__(256, 2) void k_gather(const int* __restrict__ sel,
                                                   const int* __restrict__ dkg,
                                                   const float* __restrict__ drug,
                                                   const float* __restrict__ rel,
                                                   const float* __restrict__ tail,
                                                   const float* __restrict__ W1,
                                                   const float* __restrict__ b1,
                                                   const float* __restrict__ W2,
                                                   const float* __restrict__ b2,
                                                   float* __restrict__ neigh,
                                                   float* __restrict__ psq) {
  __shared__ __align__(16) u16 Vh[4][16][72];
  __shared__ __align__(16) u16 Vl[4][16][72];
  __shared__ float rsp[4][64];
  int tid = threadIdx.x, lane = tid & 63, wv = tid >> 6;
  int quad = lane >> 4, c = lane & 15;

  if (blockIdx.x == 0 && tid < 128) psq[tid] = 0.f;   // init stats accumulators
  {                                             // W2 row-sums, 256-thread split
    int r_ = tid & 63, ks = tid >> 6;
    float s = 0.f;
    for (int k = ks * 16; k < ks * 16 + 16; k++) s += q16(W2[r_ * 64 + k]);
    rsp[ks][r_] = s;
  }
  __syncthreads();

  bf16x8 bw[4][2];
#pragma unroll
  for (int t = 0; t < 4; t++)
#pragma unroll
    for (int s = 0; s < 2; s++) {
      union { short h[8]; bf16x8 v; } u;
#pragma unroll
      for (int jj = 0; jj < 8; jj++)
        u.h[jj] = (short)rne16(W1[(s * 32 + quad * 8 + jj) * 64 + t * 16 + c]);
      bw[t][s] = u.v;
    }
  float b1t[4], w2t[4];
#pragma unroll
  for (int t = 0; t < 4; t++) {
    b1t[t] = q16(b1[t * 16 + c]);
    int rr = t * 16 + c;
    w2t[t] = rsp[0][rr] + rsp[1][rr] + rsp[2][rr] + rsp[3][rr];
  }
  float sb2 = q16(b2[lane]);
#pragma unroll
  for (int m = 32; m; m >>= 1) sb2 += __shfl_xor(sb2, m, 64);

  int d0 = (blockIdx.x * 4 + wv) * 4;           // 4 drugs per wave, grid 625
  int sv = sel[d0 * SSIZE + lane];              // 64 slots = 4 drugs x 16
  int es = sv < 0 ? 0 : sv;
  int rlv = dkg[3 * es + 2];
  int tlv = dkg[3 * es + 1];

#pragma unroll 1
  for (int dd = 0; dd < 4; dd++) {
    int d = d0 + dd;
    float dr = q16(drug[d * 64 + lane]);
#pragma unroll
    for (int e = 0; e < 16; e++) {
      int rl = __shfl(rlv, dd * 16 + e, 64);
      float v = dr * q16(rel[rl * 64 + lane]);
      u16 hb = rne16(v);
      float lo = v - bfbits2f(hb);
      Vh[wv][e][lane] = hb;
      Vl[wv][e][lane] = rne16(lo);          // exact split
    }
    bf16x8 ah[2], al[2];
#pragma unroll
    for (int s = 0; s < 2; s++) {
      ah[s] = *(const bf16x8*)&Vh[wv][c][s * 32 + quad * 8];
      al[s] = *(const bf16x8*)&Vl[wv][c][s * 32 + quad * 8];
    }
    f32x4 acc[4];
#pragma unroll
    for (int t = 0; t < 4; t++) {
      acc[t] = (f32x4){b1t[t], b1t[t], b1t[t], b1t[t]};
#pragma unroll
      for (int s = 0; s < 2; s++) {
        acc[t] = __builtin_amdgcn_mfma_f32_16x16x32_bf16(ah[s], bw[t][s], acc[t], 0, 0, 0);
        acc[t] = __builtin_amdgcn_mfma_f32_16x16x32_bf16(al[s], bw[t][s], acc[t], 0, 0, 0);
      }
    }
    float p[4] = {0.f, 0.f, 0.f, 0.f};
#pragma unroll
    for (int t = 0; t < 4; t++)
#pragma unroll
      for (int r = 0; r < 4; r++)
        p[r] = fmaf(1.f / (1.f + __expf(-acc[t][r])), w2t[t], p[r]);
#pragma unroll
    for (int m = 1; m < 16; m <<= 1) {
#pragma unroll
      for (int r = 0; r < 4; r++) p[r] += __shfl_xor(p[r], m, 64);
    }
#pragma unroll
    for (int r = 0; r < 4; r++) p[r] += sb2;
    float a0 = 0.f, a1 = 0.f, a2 = 0.f, a3 = 0.f;
#pragma unroll
    for (int e = 0; e < 16; e += 4) {
#pragma unroll
      for (int k = 0; k < 4; k++) {
        int sl = dd * 16 + e + k;
        int ee = __shfl(sv, sl, 64);
        int tl = __shfl(tlv, sl, 64);
        float sc = __shfl(p[(e + k) & 3], ((e + k) >> 2) << 4, 64);
        float tv = q16(tail[tl * 64 + lane]);
        if (ee >= 0) {
          if (k == 0) a0 = fmaf(sc, tv, a0);
          else if (k == 1) a1 = fmaf(sc, tv, a1);
          else if (k == 2) a2 = fmaf(sc, tv, a2);
          else a3 = fmaf(sc, tv, a3);
        }
      }
    }
    neigh[d * 64 + lane] = (a0 + a1) + (a2 + a3);
  }
}

// ---- Phase 5b: y = [drug | neigh] @ Wc + bc via MFMA + fused BN stats ----
__global__ __launch_bounds__(256, 2) void k_epi(const float* __restrict__ drug,
                                                const float* __restrict__ neigh,
                                                const float* __restrict__ Wc,
                                                const float* __restrict__ bc,
                                                float* __restrict__ y,
                                                float* __restrict__ ps,
                                                float* __restrict__ pq) {
  __shared__ __align__(16) u16 Ah[4][16][136];
  __shared__ __align__(16) u16 Al[4][16][72];
  __shared__ float Sp[16][64], Qp[16][64];
  int tid = threadIdx.x, lane = tid & 63, wv = tid >> 6;
  int quad = lane >> 4, c = lane & 15;

  bf16x8 bw[4][4];
#pragma unroll
  for (int t = 0; t < 4; t++)
#pragma unroll
    for (int s = 0; s < 4; s++) {
      union { short h[8]; bf16x8 v; } u;
#pragma unroll
      for (int jj = 0; jj < 8; jj++)
        u.h[jj] = (short)rne16(Wc[(s * 32 + quad * 8 + jj) * 64 + t * 16 + c]);
      bw[t][s] = u.v;
    }
  float bct[4];
#pragma unroll
  for (int t = 0; t < 4; t++) bct[t] = q16(bc[t * 16 + c]);

  int D0 = (blockIdx.x * 4 + wv) * 16;
#pragma unroll 1
  for (int rr = 0; rr < 16; rr++) {
    int d = D0 + rr;
    int dsafe = d < NDRUGS ? d : NDRUGS - 1;
    float dv = q16(drug[dsafe * 64 + lane]);
    Ah[wv][rr][lane] = rne16(dv);
    float nv = neigh[dsafe * 64 + lane];
    u16 nh = rne16(nv);
    Ah[wv][rr][64 + lane] = nh;
    Al[wv][rr][lane] = rne16(nv - bfbits2f(nh));
  }
  f32x4 acc[4];
#pragma unroll
  for (int t = 0; t < 4; t++) acc[t] = (f32x4){bct[t], bct[t], bct[t], bct[t]};
#pragma unroll
  for (int s = 0; s < 4; s++) {
    bf16x8 a = *(const bf16x8*)&Ah[wv][c][s * 32 + quad * 8];
#pragma unroll
    for (int t = 0; t < 4; t++)
      acc[t] = __builtin_amdgcn_mfma_f32_16x16x32_bf16(a, bw[t][s], acc[t], 0, 0, 0);
  }
#pragma unroll
  for (int s = 0; s < 2; s++) {
    bf16x8 a = *(const bf16x8*)&Al[wv][c][s * 32 + quad * 8];
#pragma unroll
    for (int t = 0; t < 4; t++)
      acc[t] = __builtin_amdgcn_mfma_f32_16x16x32_bf16(a, bw[t][2 + s], acc[t], 0, 0, 0);
  }
  // write y + per-lane column partials for BN stats
#pragma unroll
  for (int t = 0; t < 4; t++) {
    float s = 0.f, q = 0.f;
#pragma unroll
    for (int r = 0; r < 4; r++) {
      int row = D0 + quad * 4 + r;
      if (row < NDRUGS) {
        float v = acc[t][r];
        y[row * 64 + t * 16 + c] = v;
        s += v;
        q = fmaf(v, v, q);
      }
    }
    Sp[wv * 4 + quad][t * 16 + c] = s;
    Qp[wv * 4 + quad][t * 16 + c] = q;
  }
  __syncthreads();
  if (tid < 64) {
    float s = 0.f, q = 0.f;
#pragma unroll
    for (int p = 0; p < 16; p++) { s += Sp[p][tid]; q += Qp[p][tid]; }
    atomicAdd(&ps[tid], s);
    atomicAdd(&pq[tid], q);
  }
}

// ---- Phase 7: BN (stats inline) + passthrough copies, float4 ----
__global__ __launch_bounds__(256) void k_final(const float4* __restrict__ HFE4,
                                               const float4* __restrict__ Xv4,
                                               const float* __restrict__ gamma,
                                               const float* __restrict__ beta,
                                               const float* __restrict__ ps,
                                               const float* __restrict__ pq,
                                               float4* __restrict__ out4) {
  int i4 = blockIdx.x * 256 + threadIdx.x;
  if (i4 < 160000) {
    float4 a = HFE4[i4];
    a.x = q16(a.x); a.y = q16(a.y); a.z = q16(a.z); a.w = q16(a.w);
    out4[i4] = a;
  } else if (i4 < 320000) {
    int idx4 = i4 - 160000;
    int j0 = (idx4 * 4) & 63;
    float4 S = *(const float4*)&ps[j0];
    float4 Q = *(const float4*)&pq[j0];
    float4 v = out4[i4];                      // y, in place
    float4 r;
#define BN1(X, SS, QQ, JJ)                                                 \
    { float m = SS / 10000.f;                                              \
      float inv = rsqrtf(QQ / 10000.f - m * m + 1e-5f);                    \
      r.X = q16(fmaf(q16(gamma[JJ]) * (v.X - m), inv, q16(beta[JJ]))); }
    BN1(x, S.x, Q.x, j0 + 0)
    BN1(y, S.y, Q.y, j0 + 1)
    BN1(z, S.z, Q.z, j0 + 2)
    BN1(w, S.w, Q.w, j0 + 3)
#undef BN1
    out4[i4] = r;
  } else if (i4 < 322500) {
    float4 a = Xv4[i4 - 320000];
    a.x = q16(a.x); a.y = q16(a.y); a.z = q16(a.z); a.w = q16(a.w);
    out4[i4] = a;
  }
}

extern "C" void kernel_launch(void* const* d_in, const int* in_sizes, int n_in,
                              void* d_out, int out_size, void* d_ws, size_t ws_size,
                              hipStream_t stream) {
  const float* drug = (const float*)d_in[2];
  const float* rel  = (const float*)d_in[3];
  const float* tail = (const float*)d_in[4];
  const float* W1   = (const float*)d_in[5];
  const float* b1   = (const float*)d_in[6];
  const float* W2   = (const float*)d_in[7];
  const float* b2   = (const float*)d_in[8];
  const float* Wc   = (const float*)d_in[9];
  const float* bc   = (const float*)d_in[10];
  const float* gam  = (const float*)d_in[11];
  const float* bet  = (const float*)d_in[12];
  const int*   dkg  = (const int*)d_in[13];
  float* out = (float*)d_out;
  float* y = out + 640000;                   // Output-1 region doubles as y

  // ---- Workspace (footprint 4,760,004 B <= proven-safe 4,760,512) ----
  char* w = (char*)d_ws;
  u32*   part   = (u32*)(w);                 // NPART*10000*2 B = 3,840,000; dead after k_thr
  int*   cand   = (int*)(w);                 // 10000*96*4 = 3,840,000; overlays dead part; dead after k_fix
  float* neigh  = (float*)(w);               // 2.56 MB, overlays dead cand
  float* ps     = (float*)(w + 2600000);     // 256 B (inside dead cand region)
  float* pq     = (float*)(w + 2600256);     // 256 B
  int*   flagl  = (int*)(w + 3900000);       // 1 KB (outside part region)
  int*   nflag  = (int*)(w + 3904096);       // 4 B
  int*   sel    = (int*)(w + 4000000);       // 640 KB
  int*   cnt    = (int*)(w + 4640000);       // 40 KB
  u32*   thr    = (u32*)(w + 4680000);       // 40 KB
  int*   deg    = (int*)(w + 4720000);       // 40 KB

  // Threefry key derivation (seed 42, partitionable split semantics)
  u32 k1x, k1y, k2x, k2y, khx, khy, klx, kly;
  tf2x32(0u, 42u, 0u, 0u, k1x, k1y);   // split(key)[0] -> uniform r
  tf2x32(0u, 42u, 0u, 1u, k2x, k2y);   // split(key)[1] -> randint key
  tf2x32(k2x, k2y, 0u, 0u, khx, khy);  // split(k2)[0] -> higher_bits
  tf2x32(k2x, k2y, 0u, 1u, klx, kly);  // split(k2)[1] -> lower_bits

  k_hist<<<NPART, 256, 0, stream>>>((const int4*)dkg, part);
  k_thr<<<(NDRUGS / 2 + 255) / 256, 256, 0, stream>>>(part, deg, thr, cnt, nflag);
  k_cand<<<(NE / 4 + 255) / 256, 256, 0, stream>>>((const int4*)dkg, thr, cnt,
                                                   cand, nflag, flagl, k1x, k1y);
  k_select<<<2500, 256, 0, stream>>>(cand, cnt, deg, sel, nflag, flagl,
                                     k1x, k1y, khx, khy, klx, kly);
  k_fix<<<1, 256, 0, stream>>>(dkg, nflag, flagl, sel, k1x, k1y);
  k_gather<<<625, 256, 0, stream>>>(sel, dkg, drug, rel, tail,
                                    W1, b1, W2, b2, neigh, ps);
  k_epi<<<157, 256, 0, stream>>>(drug, neigh, Wc, bc, y, ps, pq);
  k_final<<<(322500 + 255) / 256, 256, 0, stream>>>((const float4*)d_in[0],
                                                    (const float4*)d_in[1],
                                                    gam, bet, ps, pq,
                                                    (float4*)out);
}

// Round 2
// 201.217 us; speedup vs baseline: 1.2145x; 1.0805x over previous
//
#include <hip/hip_runtime.h>
#include <stdint.h>

// ---- Problem constants ----
#define NDRUGS 10000
#define NTAILS 20000
#define NE     1000000
#define SSIZE  16
#define NPART  192          // partial-histogram blocks (u16 partials, 3.84 MB)
#define CSLOT  84           // candidate slots per drug (mean ~48, P(>84)~1e-7/drug)

typedef unsigned int  u32;
typedef unsigned short u16;
typedef unsigned long long u64;
typedef __attribute__((ext_vector_type(8))) short bf16x8;
typedef __attribute__((ext_vector_type(4))) float f32x4;
#define U64MAX 0xffffffffffffffffULL

// ---- Threefry-2x32-20 (exact JAX semantics) ----
__host__ __device__ __forceinline__ void tf2x32(u32 k0, u32 k1, u32 x0, u32 x1,
                                                u32& o0, u32& o1) {
  u32 ks2 = k0 ^ k1 ^ 0x1BD11BDAu;
  x0 += k0; x1 += k1;
#define TFR(r) { x0 += x1; x1 = (x1 << r) | (x1 >> (32 - r)); x1 ^= x0; }
  TFR(13) TFR(15) TFR(26) TFR(6)
  x0 += k1; x1 += ks2 + 1u;
  TFR(17) TFR(29) TFR(16) TFR(24)
  x0 += ks2; x1 += k0 + 2u;
  TFR(13) TFR(15) TFR(26) TFR(6)
  x0 += k0; x1 += k1 + 3u;
  TFR(17) TFR(29) TFR(16) TFR(24)
  x0 += k1; x1 += ks2 + 4u;
  TFR(13) TFR(15) TFR(26) TFR(6)
  x0 += ks2; x1 += k0 + 5u;
#undef TFR
  o0 = x0; o1 = x1;
}

__device__ __forceinline__ u32 rbits32(u32 kx, u32 ky, u32 i) {
  u32 o0, o1;
  tf2x32(kx, ky, 0u, i, o0, o1);
  return o0 ^ o1;   // partitionable fold
}
// Stable-lexsort-equivalent composite key
#define SELKEY(e) ((((u64)(rbits32(k1x, k1y, (u32)(e)) >> 9)) << 32) | (u32)(e))
#define CSWAP(x, y) { u64 lo_ = x < y ? x : y; u64 hi_ = x < y ? y : x; x = lo_; y = hi_; }

// ---- bf16 helpers (RNE, matches np/jax bf16 cast) ----
__device__ __forceinline__ float q16(float f) {
  u32 x = __builtin_bit_cast(u32, f);
  u32 lsb = (x >> 16) & 1u;
  x = (x + 0x7fffu + lsb) & 0xffff0000u;
  return __builtin_bit_cast(float, x);
}
__device__ __forceinline__ u16 rne16(float f) {
  u32 x = __builtin_bit_cast(u32, f);
  u32 lsb = (x >> 16) & 1u;
  return (u16)((x + 0x7fffu + lsb) >> 16);
}
__device__ __forceinline__ float bfbits2f(u16 b) {
  u32 x = ((u32)b) << 16;
  return __builtin_bit_cast(float, x);
}

// ---- Phase 1: degree histogram via per-block LDS hist + u16 partials ----
__global__ __launch_bounds__(256) void k_hist(const int4* __restrict__ dkg4,
                                              u32* __restrict__ part32) {
  __shared__ int hist[NDRUGS];                 // 40 KB
  for (int j = threadIdx.x; j < NDRUGS; j += 256) hist[j] = 0;
  __syncthreads();
  for (int i = blockIdx.x * 256 + threadIdx.x; i < NE / 4; i += NPART * 256) {
    int4 A = dkg4[3 * i], B = dkg4[3 * i + 1], C = dkg4[3 * i + 2];
    atomicAdd(&hist[A.x], 1);
    atomicAdd(&hist[A.w], 1);
    atomicAdd(&hist[B.z], 1);
    atomicAdd(&hist[C.y], 1);
  }
  __syncthreads();
  u32* p = part32 + blockIdx.x * (NDRUGS / 2);
  for (int j = threadIdx.x; j < NDRUGS / 2; j += 256)
    p[j] = (u32)hist[2 * j] | ((u32)hist[2 * j + 1] << 16);
}

// ---- Phase 2: reduce partials; thresholds; init nflag + BN stat shards ----
// thr guarantees: deg<=40 -> pass-all (exact, covers deg<16 extras);
// else mean ~48 candidates. cnt>=16 => candidates contain the exact top-16.
__global__ __launch_bounds__(256) void k_thr(const u32* __restrict__ part32,
                                             int* __restrict__ deg,
                                             u32* __restrict__ thr,
                                             int* __restrict__ nflag,
                                             float* __restrict__ ps,
                                             float* __restrict__ pq) {
  int t = blockIdx.x * 256 + threadIdx.x;      // one thread = 2 drugs
  if (t == 0) *nflag = 0;
  if (t < 1024) { ps[t] = 0.f; pq[t] = 0.f; }  // 16-shard BN accumulators
  if (t >= NDRUGS / 2) return;
  int d0 = 0, d1 = 0;
  for (int b = 0; b < NPART; b++) {
    u32 v = part32[b * (NDRUGS / 2) + t];
    d0 += (int)(v & 0xffffu);
    d1 += (int)(v >> 16);
  }
  int d = 2 * t;
  deg[d] = d0;  deg[d + 1] = d1;
  thr[d]     = (d0 <= 40) ? 0x800000u
                          : (402653184u + (u32)d0 - 1u) / (u32)d0;  // ceil(48*2^23/dg)
  thr[d + 1] = (d1 <= 40) ? 0x800000u
                          : (402653184u + (u32)d1 - 1u) / (u32)d1;
}

// ---- Phase 3: candidate emission; cnt padded 1 counter/64B line ----
__global__ __launch_bounds__(256) void k_cand(const int4* __restrict__ dkg4,
                                              const u32* __restrict__ thr,
                                              int* __restrict__ cntp,
                                              int* __restrict__ cand,
                                              int* __restrict__ nflag,
                                              int* __restrict__ flaglist,
                                              u32 k1x, u32 k1y) {
  __shared__ u32 thr_l[NDRUGS];               // 40 KB -> 4 blocks/CU
  for (int j = threadIdx.x; j < NDRUGS; j += 256) thr_l[j] = thr[j];
  __syncthreads();
  int i = blockIdx.x * 256 + threadIdx.x;
  if (i >= NE / 4) return;
  int4 A = dkg4[3 * i], B = dkg4[3 * i + 1], C = dkg4[3 * i + 2];
  int h[4] = {A.x, A.w, B.z, C.y};
  int e0 = 4 * i;
#pragma unroll
  for (int k = 0; k < 4; k++) {
    u32 rb = rbits32(k1x, k1y, (u32)(e0 + k));
    if ((rb >> 9) < thr_l[h[k]]) {
      int pos = atomicAdd(&cntp[h[k] * 16], 1);
      if (pos < CSLOT) cand[h[k] * CSLOT + pos] = e0 + k;
      else if (pos == CSLOT) {
        int ix = atomicAdd(nflag, 1);
        if (ix < 256) flaglist[ix] = h[k];
      }
    }
  }
}

// ---- Phase 4: wave-per-drug top-16 from candidates ----
__global__ __launch_bounds__(256) void k_select(const int* __restrict__ cand,
                                                const int* __restrict__ cntp,
                                                const int* __restrict__ deg,
                                                int* __restrict__ sel,
                                                int* __restrict__ nflag,
                                                int* __restrict__ flaglist,
                                                u32 k1x, u32 k1y,
                                                u32 khx, u32 khy,
                                                u32 klx, u32 kly) {
  __shared__ int asel[4][16];
  int tid = threadIdx.x, lane = tid & 63, wv = tid >> 6;
  int d = blockIdx.x * 4 + wv;
  if (d >= NDRUGS) return;
  int dg = deg[d], n = cntp[d * 16], off = d * CSLOT;
  if (dg <= 0) {
    if (lane < 16) sel[d * SSIZE + lane] = -1;
    return;
  }
  if (dg >= SSIZE) {
    if (n < SSIZE || n > CSLOT) {          // filter failed -> exact fallback
      if (lane == 0) {
        int ix = atomicAdd(nflag, 1);
        if (ix < 256) flaglist[ix] = d;
      }
      return;
    }
    u64 a0 = U64MAX, a1 = U64MAX;
    if (lane < n)      a0 = SELKEY(cand[off + lane]);
    if (lane + 64 < n) a1 = SELKEY(cand[off + lane + 64]);
    CSWAP(a0, a1)
    int h = 0; u32 my = 0;
#pragma unroll
    for (int r = 0; r < SSIZE; r++) {
      u64 ex = (h == 0) ? a0 : (h == 1) ? a1 : U64MAX;
      u64 g = ex;
#pragma unroll
      for (int m = 1; m < 64; m <<= 1) {
        u64 o = __shfl_xor(g, m, 64);
        g = o < g ? o : g;
      }
      if (lane == r) my = (u32)g;
      if (ex == g) h++;
    }
    if (lane < 16) sel[d * SSIZE + lane] = (int)my;
  } else {
    // deg<16: thr passed all -> n == dg; ascending extraction + extras
    u64 a0 = (lane < n) ? SELKEY(cand[off + lane]) : U64MAX;
    int h = 0;
    for (int r = 0; r < n; r++) {
      u64 ex = (h == 0) ? a0 : U64MAX;
      u64 g = ex;
#pragma unroll
      for (int m = 1; m < 64; m <<= 1) {
        u64 o = __shfl_xor(g, m, 64);
        g = o < g ? o : g;
      }
      if (lane == 0) asel[wv][r] = (int)(u32)g;
      if (ex == g) h++;
    }
    if (lane < n) sel[d * SSIZE + lane] = asel[wv][lane];
    int need = SSIZE - n;
    const u32 span = 0x7fffffffu;           // 2^31-1; 2^32 % span = 2
    if (lane < need) {
      u32 j = (u32)(d * SSIZE + lane);
      u32 hi = rbits32(khx, khy, j) % span;
      u32 lo = rbits32(klx, kly, j) % span;
      u32 u = (hi * 2u + lo) % span;        // uint32 wraparound: JAX-exact
      int idx = (int)(u % (u32)n);
      sel[d * SSIZE + n + lane] = asel[wv][idx];
    }
  }
}

// ---- Phase 4b: exact fallback for flagged drugs (normally: load, exit) ----
__global__ __launch_bounds__(256) void k_fix(const int* __restrict__ dkg,
                                             const int* __restrict__ nflag,
                                             const int* __restrict__ flaglist,
                                             int* __restrict__ sel,
                                             u32 k1x, u32 k1y) {
  int nf = *nflag;
  if (nf <= 0) return;
  if (nf > 256) nf = 256;
  __shared__ u64 pool[256 * 16];
  int tid = threadIdx.x;
  for (int f = 0; f < nf; f++) {
    int d = flaglist[f];
    u64 loc[16];
#pragma unroll
    for (int i = 0; i < 16; i++) loc[i] = U64MAX;
    u64 mx = U64MAX; int mi = 0;
    for (int e = tid; e < NE; e += 256) {
      if (dkg[3 * e] == d) {
        u64 k = SELKEY(e);
        if (k < mx) {
          loc[mi] = k; mx = 0;
          for (int i = 0; i < 16; i++)
            if (loc[i] > mx) { mx = loc[i]; mi = i; }
        }
      }
    }
#pragma unroll
    for (int i = 0; i < 16; i++) pool[tid * 16 + i] = loc[i];
    __syncthreads();
    if (tid == 0) {
      u64 best[16];
#pragma unroll
      for (int i = 0; i < 16; i++) best[i] = U64MAX;
      u64 bm = U64MAX; int bi = 0;
      for (int i = 0; i < 256 * 16; i++) {
        u64 k = pool[i];
        if (k < bm) {
          best[bi] = k; bm = 0;
          for (int j = 0; j < 16; j++)
            if (best[j] > bm) { bm = best[j]; bi = j; }
        }
      }
      for (int s = 0; s < 16; s++) sel[d * SSIZE + s] = (int)(u32)best[s];
    }
    __syncthreads();
  }
}

// ---- Phase 5 (fused): edge-MLP + neighbor gather + [drug|neigh]@Wc + BN ----
// Block covers 16 drugs = exactly one epi tile; neigh stays in LDS.
__global__ __launch_bounds__(256, 2) void k_gepi(const int* __restrict__ sel,
                                                 const int* __restrict__ dkg,
                                                 const float* __restrict__ drug,
                                                 const float* __restrict__ rel,
                                                 const float* __restrict__ tail,
                                                 const float* __restrict__ W1,
                                                 const float* __restrict__ b1,
                                                 const float* __restrict__ W2,
                                                 const float* __restrict__ b2,
                                                 const float* __restrict__ Wc,
                                                 const float* __restrict__ bc,
                                                 float* __restrict__ y,
                                                 float* __restrict__ ps,
                                                 float* __restrict__ pq) {
  __shared__ __align__(16) u16 Vh[4][16][72];
  __shared__ __align__(16) u16 Vl[4][16][72];
  __shared__ float rsp[4][64];
  __shared__ __align__(16) u16 NAh[16][136];   // [drug row][drug bf16 | neigh hi]
  __shared__ __align__(16) u16 NAl[16][72];    // neigh lo
  int tid = threadIdx.x, lane = tid & 63, wv = tid >> 6;
  int quad = lane >> 4, c = lane & 15;

  {                                             // W2 row-sums, 256-thread split
    int r_ = tid & 63, ks = tid >> 6;
    float s = 0.f;
    for (int k = ks * 16; k < ks * 16 + 16; k++) s += q16(W2[r_ * 64 + k]);
    rsp[ks][r_] = s;
  }
  __syncthreads();

  bf16x8 bw[4][2];
#pragma unroll
  for (int t = 0; t < 4; t++)
#pragma unroll
    for (int s = 0; s < 2; s++) {
      union { short h[8]; bf16x8 v; } u;
#pragma unroll
      for (int jj = 0; jj < 8; jj++)
        u.h[jj] = (short)rne16(W1[(s * 32 + quad * 8 + jj) * 64 + t * 16 + c]);
      bw[t][s] = u.v;
    }
  float b1t[4], w2t[4];
#pragma unroll
  for (int t = 0; t < 4; t++) {
    b1t[t] = q16(b1[t * 16 + c]);
    int rr = t * 16 + c;
    w2t[t] = rsp[0][rr] + rsp[1][rr] + rsp[2][rr] + rsp[3][rr];
  }
  float sb2 = q16(b2[lane]);
#pragma unroll
  for (int m = 32; m; m >>= 1) sb2 += __shfl_xor(sb2, m, 64);

  int d0 = (blockIdx.x * 4 + wv) * 4;           // 4 drugs per wave, grid 625
  int sv = sel[d0 * SSIZE + lane];              // 64 slots = 4 drugs x 16
  int es = sv < 0 ? 0 : sv;
  int rlv = dkg[3 * es + 2];
  int tlv = dkg[3 * es + 1];

#pragma unroll 1
  for (int dd = 0; dd < 4; dd++) {
    int d = d0 + dd;
    float dr = q16(drug[d * 64 + lane]);
#pragma unroll
    for (int e = 0; e < 16; e++) {
      int rl = __shfl(rlv, dd * 16 + e, 64);
      float v = dr * q16(rel[rl * 64 + lane]);
      u16 hb = rne16(v);
      float lo = v - bfbits2f(hb);
      Vh[wv][e][lane] = hb;
      Vl[wv][e][lane] = rne16(lo);          // exact split
    }
    bf16x8 ah[2], al[2];
#pragma unroll
    for (int s = 0; s < 2; s++) {
      ah[s] = *(const bf16x8*)&Vh[wv][c][s * 32 + quad * 8];
      al[s] = *(const bf16x8*)&Vl[wv][c][s * 32 + quad * 8];
    }
    f32x4 acc[4];
#pragma unroll
    for (int t = 0; t < 4; t++) {
      acc[t] = (f32x4){b1t[t], b1t[t], b1t[t], b1t[t]};
#pragma unroll
      for (int s = 0; s < 2; s++) {
        acc[t] = __builtin_amdgcn_mfma_f32_16x16x32_bf16(ah[s], bw[t][s], acc[t], 0, 0, 0);
        acc[t] = __builtin_amdgcn_mfma_f32_16x16x32_bf16(al[s], bw[t][s], acc[t], 0, 0, 0);
      }
    }
    float p[4] = {0.f, 0.f, 0.f, 0.f};
#pragma unroll
    for (int t = 0; t < 4; t++)
#pragma unroll
      for (int r = 0; r < 4; r++)
        p[r] = fmaf(1.f / (1.f + __expf(-acc[t][r])), w2t[t], p[r]);
#pragma unroll
    for (int m = 1; m < 16; m <<= 1) {
#pragma unroll
      for (int r = 0; r < 4; r++) p[r] += __shfl_xor(p[r], m, 64);
    }
#pragma unroll
    for (int r = 0; r < 4; r++) p[r] += sb2;
    float a0 = 0.f, a1 = 0.f, a2 = 0.f, a3 = 0.f;
#pragma unroll
    for (int e = 0; e < 16; e += 4) {
#pragma unroll
      for (int k = 0; k < 4; k++) {
        int sl = dd * 16 + e + k;
        int ee = __shfl(sv, sl, 64);
        int tl = __shfl(tlv, sl, 64);
        float sc = __shfl(p[(e + k) & 3], ((e + k) >> 2) << 4, 64);
        float tv = q16(tail[tl * 64 + lane]);
        if (ee >= 0) {
          if (k == 0) a0 = fmaf(sc, tv, a0);
          else if (k == 1) a1 = fmaf(sc, tv, a1);
          else if (k == 2) a2 = fmaf(sc, tv, a2);
          else a3 = fmaf(sc, tv, a3);
        }
      }
    }
    float nv = (a0 + a1) + (a2 + a3);
    int row = wv * 4 + dd;
    NAh[row][lane] = rne16(dr);
    u16 nh = rne16(nv);
    NAh[row][64 + lane] = nh;
    NAl[row][lane] = rne16(nv - bfbits2f(nh));
  }
  __syncthreads();

  // ---- epi phase: wave wv owns output column block t = wv ----
  bf16x8 bwc[4];
#pragma unroll
  for (int s = 0; s < 4; s++) {
    union { short h[8]; bf16x8 v; } u;
#pragma unroll
    for (int jj = 0; jj < 8; jj++)
      u.h[jj] = (short)rne16(Wc[(s * 32 + quad * 8 + jj) * 64 + wv * 16 + c]);
    bwc[s] = u.v;
  }
  float bct = q16(bc[wv * 16 + c]);
  f32x4 acc = (f32x4){bct, bct, bct, bct};
#pragma unroll
  for (int s = 0; s < 4; s++) {
    bf16x8 a = *(const bf16x8*)&NAh[c][s * 32 + quad * 8];
    acc = __builtin_amdgcn_mfma_f32_16x16x32_bf16(a, bwc[s], acc, 0, 0, 0);
  }
#pragma unroll
  for (int s = 0; s < 2; s++) {
    bf16x8 a = *(const bf16x8*)&NAl[c][s * 32 + quad * 8];
    acc = __builtin_amdgcn_mfma_f32_16x16x32_bf16(a, bwc[2 + s], acc, 0, 0, 0);
  }
  float ssum = 0.f, qsum = 0.f;
#pragma unroll
  for (int r = 0; r < 4; r++) {
    int row = blockIdx.x * 16 + quad * 4 + r;   // 625*16 == NDRUGS exactly
    float v = acc[r];
    y[row * 64 + wv * 16 + c] = v;
    ssum += v;
    qsum = fmaf(v, v, qsum);
  }
  ssum += __shfl_xor(ssum, 16, 64); ssum += __shfl_xor(ssum, 32, 64);
  qsum += __shfl_xor(qsum, 16, 64); qsum += __shfl_xor(qsum, 32, 64);
  if (quad == 0) {
    int sh = (blockIdx.x & 15) * 64 + wv * 16 + c;
    atomicAdd(&ps[sh], ssum);
    atomicAdd(&pq[sh], qsum);
  }
}

// ---- Phase 7: BN (16-shard stats summed inline) + passthrough copies ----
__global__ __launch_bounds__(256) void k_final(const float4* __restrict__ HFE4,
                                               const float4* __restrict__ Xv4,
                                               const float* __restrict__ gamma,
                                               const float* __restrict__ beta,
                                               const float* __restrict__ ps,
                                               const float* __restrict__ pq,
                                               float4* __restrict__ out4) {
  int i4 = blockIdx.x * 256 + threadIdx.x;
  if (i4 < 160000) {
    float4 a = HFE4[i4];
    a.x = q16(a.x); a.y = q16(a.y); a.z = q16(a.z); a.w = q16(a.w);
    out4[i4] = a;
  } else if (i4 < 320000) {
    int idx4 = i4 - 160000;
    int j0 = (idx4 * 4) & 63;
    float4 S = {0.f, 0.f, 0.f, 0.f}, Q = {0.f, 0.f, 0.f, 0.f};
#pragma unroll
    for (int sh = 0; sh < 16; sh++) {
      float4 a = *(const float4*)&ps[sh * 64 + j0];
      float4 b = *(const float4*)&pq[sh * 64 + j0];
      S.x += a.x; S.y += a.y; S.z += a.z; S.w += a.w;
      Q.x += b.x; Q.y += b.y; Q.z += b.z; Q.w += b.w;
    }
    float4 v = out4[i4];                      // y, in place
    float4 r;
#define BN1(X, SS, QQ, JJ)                                                 \
    { float m = SS / 10000.f;                                              \
      float inv = rsqrtf(QQ / 10000.f - m * m + 1e-5f);                    \
      r.X = q16(fmaf(q16(gamma[JJ]) * (v.X - m), inv, q16(beta[JJ]))); }
    BN1(x, S.x, Q.x, j0 + 0)
    BN1(y, S.y, Q.y, j0 + 1)
    BN1(z, S.z, Q.z, j0 + 2)
    BN1(w, S.w, Q.w, j0 + 3)
#undef BN1
    out4[i4] = r;
  } else if (i4 < 322500) {
    float4 a = Xv4[i4 - 320000];
    a.x = q16(a.x); a.y = q16(a.y); a.z = q16(a.z); a.w = q16(a.w);
    out4[i4] = a;
  }
}

extern "C" void kernel_launch(void* const* d_in, const int* in_sizes, int n_in,
                              void* d_out, int out_size, void* d_ws, size_t ws_size,
                              hipStream_t stream) {
  const float* drug = (const float*)d_in[2];
  const float* rel  = (const float*)d_in[3];
  const float* tail = (const float*)d_in[4];
  const float* W1   = (const float*)d_in[5];
  const float* b1   = (const float*)d_in[6];
  const float* W2   = (const float*)d_in[7];
  const float* b2   = (const float*)d_in[8];
  const float* Wc   = (const float*)d_in[9];
  const float* bc   = (const float*)d_in[10];
  const float* gam  = (const float*)d_in[11];
  const float* bet  = (const float*)d_in[12];
  const int*   dkg  = (const int*)d_in[13];
  float* out = (float*)d_out;
  float* y = out + 640000;                   // Output-1 region doubles as y

  // ---- Workspace (footprint 4,729,344 B <= proven-safe 4,760,512) ----
  char* w = (char*)d_ws;
  u32*   part   = (u32*)(w);                 // 3,840,000; dead after k_thr
  int*   cand   = (int*)(w);                 // 10000*84*4 = 3,360,000; overlays part
  int*   cntp   = (int*)(w + 3360000);       // 640,000 padded counters (1/64B line);
                                             //   overlays part tail; memset after k_thr
  int*   sel    = (int*)(w + 4000000);       // 640,000
  u32*   thr    = (u32*)(w + 4640000);       // 40,000
  int*   deg    = (int*)(w + 4680000);       // 40,000
  int*   flagl  = (int*)(w + 4720000);       // 1,024
  int*   nflag  = (int*)(w + 4721024);       // 4
  float* ps     = (float*)(w + 4721152);     // 16 shards x 64 = 4,096 B
  float* pq     = (float*)(w + 4725248);     // 4,096 B

  // Threefry key derivation (seed 42, partitionable split semantics)
  u32 k1x, k1y, k2x, k2y, khx, khy, klx, kly;
  tf2x32(0u, 42u, 0u, 0u, k1x, k1y);   // split(key)[0] -> uniform r
  tf2x32(0u, 42u, 0u, 1u, k2x, k2y);   // split(key)[1] -> randint key
  tf2x32(k2x, k2y, 0u, 0u, khx, khy);  // split(k2)[0] -> higher_bits
  tf2x32(k2x, k2y, 0u, 1u, klx, kly);  // split(k2)[1] -> lower_bits

  k_hist<<<NPART, 256, 0, stream>>>((const int4*)dkg, part);
  k_thr<<<(NDRUGS / 2 + 255) / 256, 256, 0, stream>>>(part, deg, thr, nflag, ps, pq);
  hipMemsetAsync(cntp, 0, 16 * NDRUGS * sizeof(int), stream);  // part dead here
  k_cand<<<(NE / 4 + 255) / 256, 256, 0, stream>>>((const int4*)dkg, thr, cntp,
                                                   cand, nflag, flagl, k1x, k1y);
  k_select<<<2500, 256, 0, stream>>>(cand, cntp, deg, sel, nflag, flagl,
                                     k1x, k1y, khx, khy, klx, kly);
  k_fix<<<1, 256, 0, stream>>>(dkg, nflag, flagl, sel, k1x, k1y);
  k_gepi<<<625, 256, 0, stream>>>(sel, dkg, drug, rel, tail,
                                  W1, b1, W2, b2, Wc, bc, y, ps, pq);
  k_final<<<(322500 + 255) / 256, 256, 0, stream>>>((const float4*)d_in[0],
                                                    (const float4*)d_in[1],
                                                    gam, bet, ps, pq,
                                                    (float4*)out);
}

// Round 3
// 190.494 us; speedup vs baseline: 1.2829x; 1.0563x over previous
//
#include <hip/hip_runtime.h>
#include <stdint.h>

// ---- Problem constants ----
#define NDRUGS 10000
#define NTAILS 20000
#define NE     1000000
#define SSIZE  16
#define NPART  168          // partial-histogram blocks; 168*20000B = 3.36MB fits cand region
#define CSLOT  84           // candidate slots per drug (mean ~48, P(>84)~1e-7/drug)

typedef unsigned int  u32;
typedef unsigned short u16;
typedef unsigned long long u64;
typedef __attribute__((ext_vector_type(8))) short bf16x8;
typedef __attribute__((ext_vector_type(4))) float f32x4;
#define U64MAX 0xffffffffffffffffULL

// ---- Threefry-2x32-20 (exact JAX semantics) ----
__host__ __device__ __forceinline__ void tf2x32(u32 k0, u32 k1, u32 x0, u32 x1,
                                                u32& o0, u32& o1) {
  u32 ks2 = k0 ^ k1 ^ 0x1BD11BDAu;
  x0 += k0; x1 += k1;
#define TFR(r) { x0 += x1; x1 = (x1 << r) | (x1 >> (32 - r)); x1 ^= x0; }
  TFR(13) TFR(15) TFR(26) TFR(6)
  x0 += k1; x1 += ks2 + 1u;
  TFR(17) TFR(29) TFR(16) TFR(24)
  x0 += ks2; x1 += k0 + 2u;
  TFR(13) TFR(15) TFR(26) TFR(6)
  x0 += k0; x1 += k1 + 3u;
  TFR(17) TFR(29) TFR(16) TFR(24)
  x0 += k1; x1 += ks2 + 4u;
  TFR(13) TFR(15) TFR(26) TFR(6)
  x0 += ks2; x1 += k0 + 5u;
#undef TFR
  o0 = x0; o1 = x1;
}

__device__ __forceinline__ u32 rbits32(u32 kx, u32 ky, u32 i) {
  u32 o0, o1;
  tf2x32(kx, ky, 0u, i, o0, o1);
  return o0 ^ o1;   // partitionable fold
}
// Stable-lexsort-equivalent composite key
#define SELKEY(e) ((((u64)(rbits32(k1x, k1y, (u32)(e)) >> 9)) << 32) | (u32)(e))
#define CSWAP(x, y) { u64 lo_ = x < y ? x : y; u64 hi_ = x < y ? y : x; x = lo_; y = hi_; }

// ---- bf16 helpers (RNE, matches np/jax bf16 cast) ----
__device__ __forceinline__ float q16(float f) {
  u32 x = __builtin_bit_cast(u32, f);
  u32 lsb = (x >> 16) & 1u;
  x = (x + 0x7fffu + lsb) & 0xffff0000u;
  return __builtin_bit_cast(float, x);
}
__device__ __forceinline__ u16 rne16(float f) {
  u32 x = __builtin_bit_cast(u32, f);
  u32 lsb = (x >> 16) & 1u;
  return (u16)((x + 0x7fffu + lsb) >> 16);
}
__device__ __forceinline__ float bfbits2f(u16 b) {
  u32 x = ((u32)b) << 16;
  return __builtin_bit_cast(float, x);
}

// ---- Phase 1: degree histogram via per-block LDS hist + u16 partials ----
__global__ __launch_bounds__(256) void k_hist(const int4* __restrict__ dkg4,
                                              u32* __restrict__ part32) {
  __shared__ int hist[NDRUGS];                 // 40 KB
  for (int j = threadIdx.x; j < NDRUGS; j += 256) hist[j] = 0;
  __syncthreads();
  for (int i = blockIdx.x * 256 + threadIdx.x; i < NE / 4; i += NPART * 256) {
    int4 A = dkg4[3 * i], B = dkg4[3 * i + 1], C = dkg4[3 * i + 2];
    atomicAdd(&hist[A.x], 1);
    atomicAdd(&hist[A.w], 1);
    atomicAdd(&hist[B.z], 1);
    atomicAdd(&hist[C.y], 1);
  }
  __syncthreads();
  u32* p = part32 + blockIdx.x * (NDRUGS / 2);
  for (int j = threadIdx.x; j < NDRUGS / 2; j += 256)
    p[j] = (u32)hist[2 * j] | ((u32)hist[2 * j + 1] << 16);
}

// ---- Phase 2: parallel partial reduction + thresholds + all inits ----
// Blocks 0..39: each owns 128 drug-pairs; 2 threads/pair split the 168
// partials (84 loads each, coalesced over pairs), LDS-combined. Packed-u16
// sums are carry-safe (deg <= ~200 << 65535).
// Blocks 40..44: zero cntp slots + ps/pq + nflag (regions disjoint from part).
__global__ __launch_bounds__(256) void k_red(const u32* __restrict__ part32,
                                             int* __restrict__ deg,
                                             u32* __restrict__ thr,
                                             int* __restrict__ cntp,
                                             int* __restrict__ nflag,
                                             float* __restrict__ ps,
                                             float* __restrict__ pq) {
  int tid = threadIdx.x, bx = blockIdx.x;
  if (bx < 40) {
    __shared__ u32 red[256];
    int P = bx * 128 + (tid & 127);            // drug pair index
    int half = tid >> 7;
    u32 s = 0;
    if (P < NDRUGS / 2) {
      int b0 = half * (NPART / 2);
      for (int b = b0; b < b0 + NPART / 2; b++) s += part32[b * (NDRUGS / 2) + P];
    }
    red[tid] = s;
    __syncthreads();
    if (half == 0 && P < NDRUGS / 2) {
      u32 tot = s + red[tid + 128];
      int d0 = (int)(tot & 0xffffu), d1 = (int)(tot >> 16);
      int d = 2 * P;
      deg[d] = d0;  deg[d + 1] = d1;
      thr[d]     = (d0 <= 40) ? 0x800000u
                              : (402653184u + (u32)d0 - 1u) / (u32)d0;  // ceil(48*2^23/dg)
      thr[d + 1] = (d1 <= 40) ? 0x800000u
                              : (402653184u + (u32)d1 - 1u) / (u32)d1;
    }
  } else {
    int z = (bx - 40) * 256 + tid;             // 1280 threads
    for (int d = z; d < NDRUGS; d += 1280) cntp[d * 16] = 0;
    if (bx == 40) {
      for (int i = tid; i < 1024; i += 256) { ps[i] = 0.f; pq[i] = 0.f; }
      if (tid == 0) *nflag = 0;
    }
  }
}

// ---- Phase 3: candidate emission; cnt padded 1 counter/64B line ----
__global__ __launch_bounds__(256) void k_cand(const int4* __restrict__ dkg4,
                                              const u32* __restrict__ thr,
                                              int* __restrict__ cntp,
                                              int* __restrict__ cand,
                                              int* __restrict__ nflag,
                                              int* __restrict__ flaglist,
                                              u32 k1x, u32 k1y) {
  __shared__ u32 thr_l[NDRUGS];               // 40 KB -> 4 blocks/CU
  for (int j = threadIdx.x; j < NDRUGS; j += 256) thr_l[j] = thr[j];
  __syncthreads();
  int i = blockIdx.x * 256 + threadIdx.x;
  if (i >= NE / 4) return;
  int4 A = dkg4[3 * i], B = dkg4[3 * i + 1], C = dkg4[3 * i + 2];
  int h[4] = {A.x, A.w, B.z, C.y};
  int e0 = 4 * i;
#pragma unroll
  for (int k = 0; k < 4; k++) {
    u32 rb = rbits32(k1x, k1y, (u32)(e0 + k));
    if ((rb >> 9) < thr_l[h[k]]) {
      int pos = atomicAdd(&cntp[h[k] * 16], 1);
      if (pos < CSLOT) cand[h[k] * CSLOT + pos] = e0 + k;
      else if (pos == CSLOT) {
        int ix = atomicAdd(nflag, 1);
        if (ix < 256) flaglist[ix] = h[k];
      }
    }
  }
}

// ---- Phase 4: wave-per-drug top-16 from candidates ----
__global__ __launch_bounds__(256) void k_select(const int* __restrict__ cand,
                                                const int* __restrict__ cntp,
                                                const int* __restrict__ deg,
                                                int* __restrict__ sel,
                                                int* __restrict__ nflag,
                                                int* __restrict__ flaglist,
                                                u32 k1x, u32 k1y,
                                                u32 khx, u32 khy,
                                                u32 klx, u32 kly) {
  __shared__ int asel[4][16];
  int tid = threadIdx.x, lane = tid & 63, wv = tid >> 6;
  int d = blockIdx.x * 4 + wv;
  if (d >= NDRUGS) return;
  int dg = deg[d], n = cntp[d * 16], off = d * CSLOT;
  if (dg <= 0) {
    if (lane < 16) sel[d * SSIZE + lane] = -1;
    return;
  }
  if (dg >= SSIZE) {
    if (n < SSIZE || n > CSLOT) {          // filter failed -> exact fallback
      if (lane == 0) {
        int ix = atomicAdd(nflag, 1);
        if (ix < 256) flaglist[ix] = d;
      }
      return;
    }
    u64 a0 = U64MAX, a1 = U64MAX;
    if (lane < n)      a0 = SELKEY(cand[off + lane]);
    if (lane + 64 < n) a1 = SELKEY(cand[off + lane + 64]);
    CSWAP(a0, a1)
    int h = 0; u32 my = 0;
#pragma unroll
    for (int r = 0; r < SSIZE; r++) {
      u64 ex = (h == 0) ? a0 : (h == 1) ? a1 : U64MAX;
      u64 g = ex;
#pragma unroll
      for (int m = 1; m < 64; m <<= 1) {
        u64 o = __shfl_xor(g, m, 64);
        g = o < g ? o : g;
      }
      if (lane == r) my = (u32)g;
      if (ex == g) h++;
    }
    if (lane < 16) sel[d * SSIZE + lane] = (int)my;
  } else {
    // deg<16: thr passed all -> n == dg; ascending extraction + extras
    u64 a0 = (lane < n) ? SELKEY(cand[off + lane]) : U64MAX;
    int h = 0;
    for (int r = 0; r < n; r++) {
      u64 ex = (h == 0) ? a0 : U64MAX;
      u64 g = ex;
#pragma unroll
      for (int m = 1; m < 64; m <<= 1) {
        u64 o = __shfl_xor(g, m, 64);
        g = o < g ? o : g;
      }
      if (lane == 0) asel[wv][r] = (int)(u32)g;
      if (ex == g) h++;
    }
    if (lane < n) sel[d * SSIZE + lane] = asel[wv][lane];
    int need = SSIZE - n;
    const u32 span = 0x7fffffffu;           // 2^31-1; 2^32 % span = 2
    if (lane < need) {
      u32 j = (u32)(d * SSIZE + lane);
      u32 hi = rbits32(khx, khy, j) % span;
      u32 lo = rbits32(klx, kly, j) % span;
      u32 u = (hi * 2u + lo) % span;        // uint32 wraparound: JAX-exact
      int idx = (int)(u % (u32)n);
      sel[d * SSIZE + n + lane] = asel[wv][idx];
    }
  }
}

// ---- Phase 4b: exact fallback for flagged drugs (normally: load, exit) ----
__global__ __launch_bounds__(256) void k_fix(const int* __restrict__ dkg,
                                             const int* __restrict__ nflag,
                                             const int* __restrict__ flaglist,
                                             int* __restrict__ sel,
                                             u32 k1x, u32 k1y) {
  int nf = *nflag;
  if (nf <= 0) return;
  if (nf > 256) nf = 256;
  __shared__ u64 pool[256 * 16];
  int tid = threadIdx.x;
  for (int f = 0; f < nf; f++) {
    int d = flaglist[f];
    u64 loc[16];
#pragma unroll
    for (int i = 0; i < 16; i++) loc[i] = U64MAX;
    u64 mx = U64MAX; int mi = 0;
    for (int e = tid; e < NE; e += 256) {
      if (dkg[3 * e] == d) {
        u64 k = SELKEY(e);
        if (k < mx) {
          loc[mi] = k; mx = 0;
          for (int i = 0; i < 16; i++)
            if (loc[i] > mx) { mx = loc[i]; mi = i; }
        }
      }
    }
#pragma unroll
    for (int i = 0; i < 16; i++) pool[tid * 16 + i] = loc[i];
    __syncthreads();
    if (tid == 0) {
      u64 best[16];
#pragma unroll
      for (int i = 0; i < 16; i++) best[i] = U64MAX;
      u64 bm = U64MAX; int bi = 0;
      for (int i = 0; i < 256 * 16; i++) {
        u64 k = pool[i];
        if (k < bm) {
          best[bi] = k; bm = 0;
          for (int j = 0; j < 16; j++)
            if (best[j] > bm) { bm = best[j]; bi = j; }
        }
      }
      for (int s = 0; s < 16; s++) sel[d * SSIZE + s] = (int)(u32)best[s];
    }
    __syncthreads();
  }
}

// ---- Phase 5 (fused): edge-MLP + neighbor gather + [drug|neigh]@Wc + BN ----
// Block covers 16 drugs = exactly one epi tile; neigh stays in LDS.
__global__ __launch_bounds__(256, 2) void k_gepi(const int* __restrict__ sel,
                                                 const int* __restrict__ dkg,
                                                 const float* __restrict__ drug,
                                                 const float* __restrict__ rel,
                                                 const float* __restrict__ tail,
                                                 const float* __restrict__ W1,
                                                 const float* __restrict__ b1,
                                                 const float* __restrict__ W2,
                                                 const float* __restrict__ b2,
                                                 const float* __restrict__ Wc,
                                                 const float* __restrict__ bc,
                                                 float* __restrict__ y,
                                                 float* __restrict__ ps,
                                                 float* __restrict__ pq) {
  __shared__ __align__(16) u16 Vh[4][16][72];
  __shared__ __align__(16) u16 Vl[4][16][72];
  __shared__ float rsp[4][64];
  __shared__ __align__(16) u16 NAh[16][136];   // [drug row][drug bf16 | neigh hi]
  __shared__ __align__(16) u16 NAl[16][72];    // neigh lo
  int tid = threadIdx.x, lane = tid & 63, wv = tid >> 6;
  int quad = lane >> 4, c = lane & 15;

  {                                             // W2 row-sums, 256-thread split
    int r_ = tid & 63, ks = tid >> 6;
    float s = 0.f;
    for (int k = ks * 16; k < ks * 16 + 16; k++) s += q16(W2[r_ * 64 + k]);
    rsp[ks][r_] = s;
  }
  __syncthreads();

  bf16x8 bw[4][2];
#pragma unroll
  for (int t = 0; t < 4; t++)
#pragma unroll
    for (int s = 0; s < 2; s++) {
      union { short h[8]; bf16x8 v; } u;
#pragma unroll
      for (int jj = 0; jj < 8; jj++)
        u.h[jj] = (short)rne16(W1[(s * 32 + quad * 8 + jj) * 64 + t * 16 + c]);
      bw[t][s] = u.v;
    }
  float b1t[4], w2t[4];
#pragma unroll
  for (int t = 0; t < 4; t++) {
    b1t[t] = q16(b1[t * 16 + c]);
    int rr = t * 16 + c;
    w2t[t] = rsp[0][rr] + rsp[1][rr] + rsp[2][rr] + rsp[3][rr];
  }
  float sb2 = q16(b2[lane]);
#pragma unroll
  for (int m = 32; m; m >>= 1) sb2 += __shfl_xor(sb2, m, 64);

  int d0 = (blockIdx.x * 4 + wv) * 4;           // 4 drugs per wave, grid 625
  int sv = sel[d0 * SSIZE + lane];              // 64 slots = 4 drugs x 16
  int es = sv < 0 ? 0 : sv;
  int rlv = dkg[3 * es + 2];
  int tlv = dkg[3 * es + 1];

#pragma unroll 1
  for (int dd = 0; dd < 4; dd++) {
    int d = d0 + dd;
    float dr = q16(drug[d * 64 + lane]);
#pragma unroll
    for (int e = 0; e < 16; e++) {
      int rl = __shfl(rlv, dd * 16 + e, 64);
      float v = dr * q16(rel[rl * 64 + lane]);
      u16 hb = rne16(v);
      float lo = v - bfbits2f(hb);
      Vh[wv][e][lane] = hb;
      Vl[wv][e][lane] = rne16(lo);          // exact split
    }
    bf16x8 ah[2], al[2];
#pragma unroll
    for (int s = 0; s < 2; s++) {
      ah[s] = *(const bf16x8*)&Vh[wv][c][s * 32 + quad * 8];
      al[s] = *(const bf16x8*)&Vl[wv][c][s * 32 + quad * 8];
    }
    f32x4 acc[4];
#pragma unroll
    for (int t = 0; t < 4; t++) {
      acc[t] = (f32x4){b1t[t], b1t[t], b1t[t], b1t[t]};
#pragma unroll
      for (int s = 0; s < 2; s++) {
        acc[t] = __builtin_amdgcn_mfma_f32_16x16x32_bf16(ah[s], bw[t][s], acc[t], 0, 0, 0);
        acc[t] = __builtin_amdgcn_mfma_f32_16x16x32_bf16(al[s], bw[t][s], acc[t], 0, 0, 0);
      }
    }
    float p[4] = {0.f, 0.f, 0.f, 0.f};
#pragma unroll
    for (int t = 0; t < 4; t++)
#pragma unroll
      for (int r = 0; r < 4; r++)
        p[r] = fmaf(1.f / (1.f + __expf(-acc[t][r])), w2t[t], p[r]);
#pragma unroll
    for (int m = 1; m < 16; m <<= 1) {
#pragma unroll
      for (int r = 0; r < 4; r++) p[r] += __shfl_xor(p[r], m, 64);
    }
#pragma unroll
    for (int r = 0; r < 4; r++) p[r] += sb2;
    float a0 = 0.f, a1 = 0.f, a2 = 0.f, a3 = 0.f;
#pragma unroll
    for (int e = 0; e < 16; e += 4) {
#pragma unroll
      for (int k = 0; k < 4; k++) {
        int sl = dd * 16 + e + k;
        int ee = __shfl(sv, sl, 64);
        int tl = __shfl(tlv, sl, 64);
        float sc = __shfl(p[(e + k) & 3], ((e + k) >> 2) << 4, 64);
        float tv = q16(tail[tl * 64 + lane]);
        if (ee >= 0) {
          if (k == 0) a0 = fmaf(sc, tv, a0);
          else if (k == 1) a1 = fmaf(sc, tv, a1);
          else if (k == 2) a2 = fmaf(sc, tv, a2);
          else a3 = fmaf(sc, tv, a3);
        }
      }
    }
    float nv = (a0 + a1) + (a2 + a3);
    int row = wv * 4 + dd;
    NAh[row][lane] = rne16(dr);
    u16 nh = rne16(nv);
    NAh[row][64 + lane] = nh;
    NAl[row][lane] = rne16(nv - bfbits2f(nh));
  }
  __syncthreads();

  // ---- epi phase: wave wv owns output column block t = wv ----
  bf16x8 bwc[4];
#pragma unroll
  for (int s = 0; s < 4; s++) {
    union { short h[8]; bf16x8 v; } u;
#pragma unroll
    for (int jj = 0; jj < 8; jj++)
      u.h[jj] = (short)rne16(Wc[(s * 32 + quad * 8 + jj) * 64 + wv * 16 + c]);
    bwc[s] = u.v;
  }
  float bct = q16(bc[wv * 16 + c]);
  f32x4 acc = (f32x4){bct, bct, bct, bct};
#pragma unroll
  for (int s = 0; s < 4; s++) {
    bf16x8 a = *(const bf16x8*)&NAh[c][s * 32 + quad * 8];
    acc = __builtin_amdgcn_mfma_f32_16x16x32_bf16(a, bwc[s], acc, 0, 0, 0);
  }
#pragma unroll
  for (int s = 0; s < 2; s++) {
    bf16x8 a = *(const bf16x8*)&NAl[c][s * 32 + quad * 8];
    acc = __builtin_amdgcn_mfma_f32_16x16x32_bf16(a, bwc[2 + s], acc, 0, 0, 0);
  }
  float ssum = 0.f, qsum = 0.f;
#pragma unroll
  for (int r = 0; r < 4; r++) {
    int row = blockIdx.x * 16 + quad * 4 + r;   // 625*16 == NDRUGS exactly
    float v = acc[r];
    y[row * 64 + wv * 16 + c] = v;
    ssum += v;
    qsum = fmaf(v, v, qsum);
  }
  ssum += __shfl_xor(ssum, 16, 64); ssum += __shfl_xor(ssum, 32, 64);
  qsum += __shfl_xor(qsum, 16, 64); qsum += __shfl_xor(qsum, 32, 64);
  if (quad == 0) {
    int sh = (blockIdx.x & 15) * 64 + wv * 16 + c;
    atomicAdd(&ps[sh], ssum);
    atomicAdd(&pq[sh], qsum);
  }
}

// ---- Phase 7: BN (16-shard stats summed inline) + passthrough copies ----
__global__ __launch_bounds__(256) void k_final(const float4* __restrict__ HFE4,
                                               const float4* __restrict__ Xv4,
                                               const float* __restrict__ gamma,
                                               const float* __restrict__ beta,
                                               const float* __restrict__ ps,
                                               const float* __restrict__ pq,
                                               float4* __restrict__ out4) {
  int i4 = blockIdx.x * 256 + threadIdx.x;
  if (i4 < 160000) {
    float4 a = HFE4[i4];
    a.x = q16(a.x); a.y = q16(a.y); a.z = q16(a.z); a.w = q16(a.w);
    out4[i4] = a;
  } else if (i4 < 320000) {
    int idx4 = i4 - 160000;
    int j0 = (idx4 * 4) & 63;
    float4 S = {0.f, 0.f, 0.f, 0.f}, Q = {0.f, 0.f, 0.f, 0.f};
#pragma unroll
    for (int sh = 0; sh < 16; sh++) {
      float4 a = *(const float4*)&ps[sh * 64 + j0];
      float4 b = *(const float4*)&pq[sh * 64 + j0];
      S.x += a.x; S.y += a.y; S.z += a.z; S.w += a.w;
      Q.x += b.x; Q.y += b.y; Q.z += b.z; Q.w += b.w;
    }
    float4 v = out4[i4];                      // y, in place
    float4 r;
#define BN1(X, SS, QQ, JJ)                                                 \
    { float m = SS / 10000.f;                                              \
      float inv = rsqrtf(QQ / 10000.f - m * m + 1e-5f);                    \
      r.X = q16(fmaf(q16(gamma[JJ]) * (v.X - m), inv, q16(beta[JJ]))); }
    BN1(x, S.x, Q.x, j0 + 0)
    BN1(y, S.y, Q.y, j0 + 1)
    BN1(z, S.z, Q.z, j0 + 2)
    BN1(w, S.w, Q.w, j0 + 3)
#undef BN1
    out4[i4] = r;
  } else if (i4 < 322500) {
    float4 a = Xv4[i4 - 320000];
    a.x = q16(a.x); a.y = q16(a.y); a.z = q16(a.z); a.w = q16(a.w);
    out4[i4] = a;
  }
}

extern "C" void kernel_launch(void* const* d_in, const int* in_sizes, int n_in,
                              void* d_out, int out_size, void* d_ws, size_t ws_size,
                              hipStream_t stream) {
  const float* drug = (const float*)d_in[2];
  const float* rel  = (const float*)d_in[3];
  const float* tail = (const float*)d_in[4];
  const float* W1   = (const float*)d_in[5];
  const float* b1   = (const float*)d_in[6];
  const float* W2   = (const float*)d_in[7];
  const float* b2   = (const float*)d_in[8];
  const float* Wc   = (const float*)d_in[9];
  const float* bc   = (const float*)d_in[10];
  const float* gam  = (const float*)d_in[11];
  const float* bet  = (const float*)d_in[12];
  const int*   dkg  = (const int*)d_in[13];
  float* out = (float*)d_out;
  float* y = out + 640000;                   // Output-1 region doubles as y

  // ---- Workspace (footprint 4,729,344 B <= proven-safe 4,760,512) ----
  char* w = (char*)d_ws;
  u32*   part   = (u32*)(w);                 // NPART*5000*4 = 3,360,000; dead after k_red
  int*   cand   = (int*)(w);                 // 10000*84*4 = 3,360,000; overlays part
  int*   cntp   = (int*)(w + 3360000);       // 640,000 padded counters (1/64B line);
                                             //   DISJOINT from part (NPART=168) -> k_red may zero it
  int*   sel    = (int*)(w + 4000000);       // 640,000
  u32*   thr    = (u32*)(w + 4640000);       // 40,000
  int*   deg    = (int*)(w + 4680000);       // 40,000
  int*   flagl  = (int*)(w + 4720000);       // 1,024
  int*   nflag  = (int*)(w + 4721024);       // 4
  float* ps     = (float*)(w + 4721152);     // 16 shards x 64 = 4,096 B
  float* pq     = (float*)(w + 4725248);     // 4,096 B

  // Threefry key derivation (seed 42, partitionable split semantics)
  u32 k1x, k1y, k2x, k2y, khx, khy, klx, kly;
  tf2x32(0u, 42u, 0u, 0u, k1x, k1y);   // split(key)[0] -> uniform r
  tf2x32(0u, 42u, 0u, 1u, k2x, k2y);   // split(key)[1] -> randint key
  tf2x32(k2x, k2y, 0u, 0u, khx, khy);  // split(k2)[0] -> higher_bits
  tf2x32(k2x, k2y, 0u, 1u, klx, kly);  // split(k2)[1] -> lower_bits

  k_hist<<<NPART, 256, 0, stream>>>((const int4*)dkg, part);
  k_red<<<45, 256, 0, stream>>>(part, deg, thr, cntp, nflag, ps, pq);
  k_cand<<<(NE / 4 + 255) / 256, 256, 0, stream>>>((const int4*)dkg, thr, cntp,
                                                   cand, nflag, flagl, k1x, k1y);
  k_select<<<2500, 256, 0, stream>>>(cand, cntp, deg, sel, nflag, flagl,
                                     k1x, k1y, khx, khy, klx, kly);
  k_fix<<<1, 256, 0, stream>>>(dkg, nflag, flagl, sel, k1x, k1y);
  k_gepi<<<625, 256, 0, stream>>>(sel, dkg, drug, rel, tail,
                                  W1, b1, W2, b2, Wc, bc, y, ps, pq);
  k_final<<<(322500 + 255) / 256, 256, 0, stream>>>((const float4*)d_in[0],
                                                    (const float4*)d_in[1],
                                                    gam, bet, ps, pq,
                                                    (float4*)out);
}